// Round 2
// baseline (438.480 us; speedup 1.0000x reference)
//
#include <hip/hip_runtime.h>

// DigitCaps matvec: u_hat[b,r,c,o] = sum_i W[r,c,o,i]*x[b,r,i] + bias[o]
// B=512 R=1152 C=10 O=16 I=8. All tensors FLOAT32 (per reference dtype).
// R1 diagnosis: R0's bf16 interpretation produced NaN (f32 read as bf16) ->
// buffers are f32. Memory-bound: 377 MB out write dominates, floor ~64 us.

#define B_ 512
#define R_ 1152
#define C_ 10
#define O_ 16
#define I_ 8
#define CO_ 160               // C*O, contiguous inner extent per (b,r)
#define SLOTS 40              // 160 outputs / 4 per thread
#define GROUPS 8              // batch rows in flight per block
#define NTHREADS (GROUPS * SLOTS)   // 320 = 5 waves, zero idle lanes
#define BATCH_PER_BLOCK 256   // grid.y = 2 splits the batch loop

__global__ __launch_bounds__(NTHREADS) void digitcaps_kernel(
    const float* __restrict__ x,     // [B,R,I]
    const float* __restrict__ W,     // [R,C,O,I]
    const float* __restrict__ bias,  // [O]
    float* __restrict__ out)         // [B,R,C,O]
{
    const int r = blockIdx.x;
    const int t = threadIdx.x;
    const int g = t / SLOTS;          // batch group 0..7
    const int s = t - g * SLOTS;      // slot 0..39: c = s>>2, o-quad = s&3

    // W fragment for this (r, c, o-quad): 4 rows x 8 i = 32 f32 = 128B contiguous.
    // Flat element offset: ((r*C + c)*O + (s&3)*4)*I = (r*CO_ + s*4)*I
    const float4* wp = (const float4*)(W + ((size_t)r * CO_ + (size_t)s * 4) * I_);
    float w[4][8];
#pragma unroll
    for (int j = 0; j < 4; ++j) {
        float4 lo = wp[2 * j];
        float4 hi = wp[2 * j + 1];
        w[j][0] = lo.x; w[j][1] = lo.y; w[j][2] = lo.z; w[j][3] = lo.w;
        w[j][4] = hi.x; w[j][5] = hi.y; w[j][6] = hi.z; w[j][7] = hi.w;
    }

    // bias for this o-quad: 4 f32 = 16B
    float4 bv = ((const float4*)bias)[s & 3];
    float bsf[4] = {bv.x, bv.y, bv.z, bv.w};

    const int b0 = blockIdx.y * BATCH_PER_BLOCK + g;
    const float* xp = x + ((size_t)b0 * R_ + r) * I_;
    float*       op = out + ((size_t)b0 * R_ + r) * CO_ + (size_t)s * 4;

    for (int it = 0; it < BATCH_PER_BLOCK / GROUPS; ++it) {
        // x[b,r,0:8] — two 16B loads, uniform across the 40-lane group (cache broadcast)
        float4 xlo = ((const float4*)xp)[0];
        float4 xhi = ((const float4*)xp)[1];
        float xf[8] = {xlo.x, xlo.y, xlo.z, xlo.w, xhi.x, xhi.y, xhi.z, xhi.w};

        float acc[4];
#pragma unroll
        for (int j = 0; j < 4; ++j) acc[j] = bsf[j];
#pragma unroll
        for (int i = 0; i < 8; ++i)
#pragma unroll
            for (int j = 0; j < 4; ++j)
                acc[j] = fmaf(xf[i], w[j][i], acc[j]);

        // 4 contiguous f32 outputs, one 16B store (group writes 640B contiguous)
        float4 ov = {acc[0], acc[1], acc[2], acc[3]};
        *(float4*)op = ov;

        xp += (size_t)GROUPS * R_ * I_;
        op += (size_t)GROUPS * R_ * CO_;
    }
}

extern "C" void kernel_launch(void* const* d_in, const int* in_sizes, int n_in,
                              void* d_out, int out_size, void* d_ws, size_t ws_size,
                              hipStream_t stream) {
    const float* x    = (const float*)d_in[0];
    const float* W    = (const float*)d_in[1];
    const float* bias = (const float*)d_in[2];
    float* out        = (float*)d_out;

    dim3 grid(R_, B_ / BATCH_PER_BLOCK);  // (1152, 2)
    digitcaps_kernel<<<grid, NTHREADS, 0, stream>>>(x, W, bias, out);
}